// Round 2
// baseline (339.532 us; speedup 1.0000x reference)
//
#include <hip/hip_runtime.h>
#include <hip/hip_bf16.h>
#include <stdint.h>

#define BN 8192
#define DK 1024
#define NT (DK / 32)          // 32 K-tiles of BK=32
#define LSMOOTH 0.1f
#define EPSF 1e-7f

typedef __bf16 bf16x8 __attribute__((ext_vector_type(8)));
typedef float f32x4 __attribute__((ext_vector_type(4)));

__device__ __forceinline__ unsigned short f2bf(float f) {
  union { float f; uint32_t u; } v; v.f = f;
  uint32_t u = v.u;
  u += 0x7fffu + ((u >> 16) & 1u);   // round-to-nearest-even
  return (unsigned short)(u >> 16);
}

// ---------------- prep: f32 -> bf16 conversion + row squared norms ----------------
__global__ __launch_bounds__(256) void prep_kernel(
    const float* __restrict__ sign, const float* __restrict__ text,
    unsigned short* __restrict__ Abf, unsigned short* __restrict__ Bbf,
    float* __restrict__ xx, float* __restrict__ yy) {
  const int b = blockIdx.x;          // 0..2*BN-1
  const int row = b & (BN - 1);
  const bool isB = b >= BN;
  const float4* src = (const float4*)((isB ? text : sign) + (size_t)row * DK);
  ushort4* dst = (ushort4*)((isB ? Bbf : Abf) + (size_t)row * DK);
  const int t = threadIdx.x;         // 256 threads, 1 float4 each (DK/4 = 256)
  float4 v = src[t];
  ushort4 o;
  o.x = f2bf(v.x); o.y = f2bf(v.y); o.z = f2bf(v.z); o.w = f2bf(v.w);
  dst[t] = o;
  float ss = v.x * v.x + v.y * v.y + v.z * v.z + v.w * v.w;
  #pragma unroll
  for (int off = 32; off; off >>= 1) ss += __shfl_down(ss, off);
  __shared__ float red[4];
  if ((t & 63) == 0) red[t >> 6] = ss;
  __syncthreads();
  if (t == 0) (isB ? yy : xx)[row] = red[0] + red[1] + red[2] + red[3];
}

// ---------------- fused GEMM (256x256 tile, BK=32, 4-slot LDS pipeline) ----------------
// 8 waves (2M x 4N), per-wave 128x64 output. Counted vmcnt(4): tile t+2's loads stay in
// flight across the barrier while tile t computes (T3+T4). setprio around MFMA (T5).
// LDS rows are 64B -> ds_read_b128 fragment pattern is bank-uniform, no swizzle needed.
__global__ __launch_bounds__(512, 2) void gemm_fused(
    const unsigned short* __restrict__ Abf, const unsigned short* __restrict__ Bbf,
    const float* __restrict__ xx, const float* __restrict__ yy,
    const float* __restrict__ p_log_tau, const float* __restrict__ p_margin,
    float* __restrict__ row_partial, float* __restrict__ accums) {
  __shared__ __align__(16) char lds[131072];   // 4 slots x (A 16KB + B 16KB)

  const int tid = threadIdx.x;
  const int wave = tid >> 6, lane = tid & 63;
  const int l15 = lane & 15, g4 = lane >> 4;
  const int waveM = wave >> 2, waveN = wave & 3;        // 2 x 4
  const int bx = blockIdx.x, by = blockIdx.y;
  const int blockRow = by * 256, blockCol = bx * 256;

  // staging: 512 threads x 16B = 8KB = 128 rows (64B each) per call; 4 calls/K-tile
  const int srow = tid >> 2;                             // row within 128-row half
  const int schunk = tid & 3;                            // 16B chunk in row
  const size_t aoff = (size_t)(blockRow + srow) * DK + schunk * 8;   // ushort units
  const size_t boff = (size_t)(blockCol + srow) * DK + schunk * 8;
  const int ldst = wave * 1024;                          // wave-uniform dest in call region

#define STAGE(kt, slot) do {                                                              \
    char* base_ = lds + (slot) * 32768;                                                   \
    const unsigned short* a0_ = Abf + aoff + (kt) * 32;                                   \
    const unsigned short* b0_ = Bbf + boff + (kt) * 32;                                   \
    __builtin_amdgcn_global_load_lds((const __attribute__((address_space(1))) void*)a0_,  \
        (__attribute__((address_space(3))) void*)(base_ + ldst), 16, 0, 0);               \
    __builtin_amdgcn_global_load_lds((const __attribute__((address_space(1))) void*)(a0_ + 128 * DK), \
        (__attribute__((address_space(3))) void*)(base_ + 8192 + ldst), 16, 0, 0);        \
    __builtin_amdgcn_global_load_lds((const __attribute__((address_space(1))) void*)b0_,  \
        (__attribute__((address_space(3))) void*)(base_ + 16384 + ldst), 16, 0, 0);       \
    __builtin_amdgcn_global_load_lds((const __attribute__((address_space(1))) void*)(b0_ + 128 * DK), \
        (__attribute__((address_space(3))) void*)(base_ + 24576 + ldst), 16, 0, 0);       \
  } while (0)

  f32x4 acc[8][4];
  #pragma unroll
  for (int m = 0; m < 8; ++m)
    #pragma unroll
    for (int n = 0; n < 4; ++n)
      acc[m][n] = (f32x4){0.f, 0.f, 0.f, 0.f};

  // per-lane fragment byte offsets (row stride 64B, k-chunk = g4*16B)
  const int a_off = (waveM * 128 + l15) * 64 + g4 * 16;
  const int b_off = 16384 + (waveN * 64 + l15) * 64 + g4 * 16;

  // prologue: stage tiles 0,1; wait tile 0 (all but newest 4 loads)
  STAGE(0, 0);
  STAGE(1, 1);
  asm volatile("s_waitcnt vmcnt(4)" ::: "memory");
  __builtin_amdgcn_s_barrier();
  asm volatile("" ::: "memory");

  for (int t = 0; t < NT; ++t) {
    if (t + 2 < NT) STAGE(t + 2, (t + 2) & 3);
    const char* sb = lds + (t & 3) * 32768;
    bf16x8 af[8], bfr[4];
    #pragma unroll
    for (int m = 0; m < 8; ++m) af[m] = *(const bf16x8*)(sb + a_off + m * 1024);
    #pragma unroll
    for (int n = 0; n < 4; ++n) bfr[n] = *(const bf16x8*)(sb + b_off + n * 1024);
    __builtin_amdgcn_s_setprio(1);
    #pragma unroll
    for (int m = 0; m < 8; ++m)
      #pragma unroll
      for (int n = 0; n < 4; ++n)
        acc[m][n] = __builtin_amdgcn_mfma_f32_16x16x32_bf16(af[m], bfr[n], acc[m][n], 0, 0, 0);
    __builtin_amdgcn_s_setprio(0);
    if (t + 2 < NT) asm volatile("s_waitcnt vmcnt(4)" ::: "memory");
    else            asm volatile("s_waitcnt vmcnt(0)" ::: "memory");
    __builtin_amdgcn_s_barrier();
    asm volatile("" ::: "memory");
  }
#undef STAGE

  // ---- fused epilogue: poincare dist, exp-sums, dist sums ----
  const float lt = *p_log_tau;
  const float mg = *p_margin;
  const float marg = fmaxf(mg, 0.f);
  const float tau = 1.99f / (1.f + __expf(-lt)) + 0.01f;
  const float ninv_tau = -1.f / tau;
  const float em = __expf(-marg);          // diagonal: exp(s_ii - C) = exp(-d/tau)*exp(-marg)

  float yyj[4], omy[4]; int gj[4];
  #pragma unroll
  for (int n = 0; n < 4; ++n) {
    gj[n] = blockCol + waveN * 64 + n * 16 + l15;        // C/D col = lane&15
    yyj[n] = yy[gj[n]];
    omy[n] = 1.f - yyj[n];
  }

  float d_tot = 0.f, d_diag = 0.f;
  float* rsum = (float*)lds;               // reuse LDS: [256 rows][4 waveN] partials

  #pragma unroll
  for (int m = 0; m < 8; ++m) {
    #pragma unroll
    for (int r = 0; r < 4; ++r) {
      const int gi = blockRow + waveM * 128 + m * 16 + g4 * 4 + r;  // C/D row
      const float xxi = xx[gi];
      const float omx = 1.f - xxi;
      float e_acc = 0.f;
      #pragma unroll
      for (int n = 0; n < 4; ++n) {
        const float xy = acc[m][n][r];
        const float sq = fmaxf(xxi + yyj[n] - 2.f * xy, 0.f);
        const float denom = fmaxf(omx * omy[n], EPSF);
        float arg = __builtin_fmaf(2.f * sq, __builtin_amdgcn_rcpf(denom), 1.f);
        arg = fmaxf(arg, 1.f + EPSF);
        const float w = arg + __builtin_amdgcn_sqrtf((arg - 1.f) * (arg + 1.f));
        const float dist = __logf(w);                    // arccosh
        float e = __expf(dist * ninv_tau);               // exp(score - C), non-diag
        const bool dg = (gi == gj[n]);
        d_tot += dist;
        d_diag += dg ? dist : 0.f;
        e = dg ? e * em : e;
        e_acc += e;
      }
      e_acc += __shfl_xor(e_acc, 1);
      e_acc += __shfl_xor(e_acc, 2);
      e_acc += __shfl_xor(e_acc, 4);
      e_acc += __shfl_xor(e_acc, 8);
      if (l15 == 0) {
        const int rloc = waveM * 128 + m * 16 + g4 * 4 + r;
        rsum[rloc * 4 + waveN] = e_acc;
      }
    }
  }

  // block-level scalar reductions -> 2 atomics per wave
  #pragma unroll
  for (int off = 32; off; off >>= 1) {
    d_tot += __shfl_down(d_tot, off);
    d_diag += __shfl_down(d_diag, off);
  }
  if (lane == 0) {
    atomicAdd(&accums[0], d_tot);
    atomicAdd(&accums[1], d_diag);
  }

  __syncthreads();
  if (tid < 256) {
    const float rs = rsum[tid * 4 + 0] + rsum[tid * 4 + 1] + rsum[tid * 4 + 2] + rsum[tid * 4 + 3];
    row_partial[(size_t)bx * BN + blockRow + tid] = rs;
  }
}

// ---------------- finalize: sum col-tile partials, log, final linear combo ----------------
__global__ __launch_bounds__(1024) void finalize_kernel(
    const float* __restrict__ row_partial, const float* __restrict__ accums,
    const float* __restrict__ p_log_tau, const float* __restrict__ p_margin,
    float* __restrict__ out) {
  const int t = threadIdx.x;
  float lsum = 0.f;
  for (int i = t; i < BN; i += 1024) {
    float s = 0.f;
    #pragma unroll
    for (int c = 0; c < 32; ++c) s += row_partial[(size_t)c * BN + i];
    lsum += __logf(s);
  }
  #pragma unroll
  for (int off = 32; off; off >>= 1) lsum += __shfl_down(lsum, off);
  __shared__ float red[16];
  if ((t & 63) == 0) red[t >> 6] = lsum;
  __syncthreads();
  if (t == 0) {
    float total = 0.f;
    #pragma unroll
    for (int w = 0; w < 16; ++w) total += red[w];
    const float lt = *p_log_tau;
    const float mg = *p_margin;
    const float marg = fmaxf(mg, 0.f);
    const float tau = 1.99f / (1.f + __expf(-lt)) + 0.01f;
    const float C = marg;
    const float d_tot = accums[0];
    const float d_diag = accums[1];
    const float bf = (float)BN;
    const float mean_lse = total / bf + C;
    const float sum_scores = -d_tot / tau + marg * (bf * bf - bf);  // margin term closed-form
    const float sum_diag_scores = -d_diag / tau;
    const float loss = mean_lse
                     - (1.f - LSMOOTH) * (sum_diag_scores / bf)
                     - LSMOOTH * (sum_scores / (bf * bf));
    out[0] = loss;
    out[1] = d_diag / bf;   // pos_dist
    out[2] = tau;
    out[3] = mg;            // maximum(margin, margin) == margin
  }
}

extern "C" void kernel_launch(void* const* d_in, const int* in_sizes, int n_in,
                              void* d_out, int out_size, void* d_ws, size_t ws_size,
                              hipStream_t stream) {
  const float* sign = (const float*)d_in[0];
  const float* text = (const float*)d_in[1];
  const float* p_log_tau = (const float*)d_in[2];
  const float* p_margin = (const float*)d_in[3];
  float* out = (float*)d_out;

  char* ws = (char*)d_ws;
  unsigned short* Abf = (unsigned short*)ws;                         // 16 MiB
  unsigned short* Bbf = (unsigned short*)(ws + (size_t)BN * DK * 2); // 16 MiB
  float* xx = (float*)(ws + (size_t)BN * DK * 4);
  float* yy = xx + BN;
  float* row_partial = yy + BN;                                      // 32 x 8192 floats = 1 MiB
  float* accums = row_partial + 32 * BN;                             // 2 floats

  hipMemsetAsync(accums, 0, 2 * sizeof(float), stream);
  prep_kernel<<<dim3(2 * BN), 256, 0, stream>>>(sign, text, Abf, Bbf, xx, yy);
  gemm_fused<<<dim3(BN / 256, BN / 256), 512, 0, stream>>>(
      Abf, Bbf, xx, yy, p_log_tau, p_margin, row_partial, accums);
  finalize_kernel<<<1, 1024, 0, stream>>>(row_partial, accums, p_log_tau, p_margin, out);
}

// Round 3
// 257.978 us; speedup vs baseline: 1.3161x; 1.3161x over previous
//
#include <hip/hip_runtime.h>
#include <hip/hip_bf16.h>
#include <stdint.h>

#define BN 8192
#define DK 1024
#define BK 32
#define NT (DK / BK)          // 32 K-tiles
#define LSMOOTH 0.1f
#define EPSF 1e-7f
#define LN2F 0.69314718055994531f

typedef __bf16 bf16x8 __attribute__((ext_vector_type(8)));
typedef float f32x4 __attribute__((ext_vector_type(4)));

__device__ __forceinline__ unsigned short f2bf(float f) {
  union { float f; uint32_t u; } v; v.f = f;
  uint32_t u = v.u;
  u += 0x7fffu + ((u >> 16) & 1u);   // round-to-nearest-even
  return (unsigned short)(u >> 16);
}

// ---------------- prep: f32 -> bf16 conversion + row squared norms ----------------
__global__ __launch_bounds__(256) void prep_kernel(
    const float* __restrict__ sign, const float* __restrict__ text,
    unsigned short* __restrict__ Abf, unsigned short* __restrict__ Bbf,
    float* __restrict__ xx, float* __restrict__ yy) {
  const int b = blockIdx.x;          // 0..2*BN-1
  const int row = b & (BN - 1);
  const bool isB = b >= BN;
  const float4* src = (const float4*)((isB ? text : sign) + (size_t)row * DK);
  ushort4* dst = (ushort4*)((isB ? Bbf : Abf) + (size_t)row * DK);
  const int t = threadIdx.x;         // 256 threads, 1 float4 each (DK/4 = 256)
  float4 v = src[t];
  ushort4 o;
  o.x = f2bf(v.x); o.y = f2bf(v.y); o.z = f2bf(v.z); o.w = f2bf(v.w);
  dst[t] = o;
  float ss = v.x * v.x + v.y * v.y + v.z * v.z + v.w * v.w;
  #pragma unroll
  for (int off = 32; off; off >>= 1) ss += __shfl_down(ss, off);
  __shared__ float red[4];
  if ((t & 63) == 0) red[t >> 6] = ss;
  __syncthreads();
  if (t == 0) (isB ? yy : xx)[row] = red[0] + red[1] + red[2] + red[3];
}

// ---------------- fused GEMM (256x256 tile, BK=32, 4-slot pipeline, 2 phases/K-tile) --
// 8 waves (2M x 4N), per-wave 128x64 output. Stage lead = 2 K-tiles, counted vmcnt(4)
// once per K-tile (never 0 in steady state). Chunk-XOR swizzle (both-sides involution)
// kills the 8-way bank conflict of 64B rows. setprio(1) around each 16-MFMA cluster.
__global__ __launch_bounds__(512, 2) void gemm_fused(
    const unsigned short* __restrict__ Abf, const unsigned short* __restrict__ Bbf,
    const float* __restrict__ xx, const float* __restrict__ yy,
    const float* __restrict__ p_log_tau, const float* __restrict__ p_margin,
    float* __restrict__ row_partial, float* __restrict__ accums) {
  __shared__ __align__(16) char lds[131072];   // 4 slots x (A 16KB + B 16KB)

  const int tid = threadIdx.x;
  const int wave = tid >> 6, lane = tid & 63;
  const int l15 = lane & 15, g4 = lane >> 4;
  const int waveM = wave >> 2, waveN = wave & 3;        // 2 x 4
  const int bx = blockIdx.x, by = blockIdx.y;
  const int blockRow = by * 256, blockCol = bx * 256;

  // ---- staging map: thread t covers (row t>>2, 16B-chunk t&3) of a 128-row half ----
  // source chunk is pre-swizzled so that the swizzled ds_read below sees row-major data
  const int srow = tid >> 2, schunk = tid & 3;
  const int swc = schunk ^ ((srow >> 1) & 3);           // involution on chunk bits
  const unsigned short* aSrc = Abf + (size_t)(blockRow + srow) * DK + swc * 8;
  const unsigned short* bSrc = Bbf + (size_t)(blockCol + srow) * DK + swc * 8;
  const int ldst = wave * 1024;                         // wave-uniform 1KB within 8KB

#define GLL(gp, lp) __builtin_amdgcn_global_load_lds(                                   \
      (const __attribute__((address_space(1))) void*)(gp),                             \
      (__attribute__((address_space(3))) void*)(lp), 16, 0, 0)
#define STAGE_A(kt) do { char* b_ = lds + ((kt) & 3) * 32768;                           \
    const unsigned short* s_ = aSrc + (kt) * BK;                                        \
    GLL(s_, b_ + ldst); GLL(s_ + 128 * DK, b_ + 8192 + ldst); } while (0)
#define STAGE_B(kt) do { char* b_ = lds + ((kt) & 3) * 32768 + 16384;                   \
    const unsigned short* s_ = bSrc + (kt) * BK;                                        \
    GLL(s_, b_ + ldst); GLL(s_ + 128 * DK, b_ + 8192 + ldst); } while (0)

  f32x4 acc[8][4];
  #pragma unroll
  for (int m = 0; m < 8; ++m)
    #pragma unroll
    for (int n = 0; n < 4; ++n)
      acc[m][n] = (f32x4){0.f, 0.f, 0.f, 0.f};

  // fragment read offsets: row-major 64B rows, chunk XOR-swizzled (same involution)
  const int sel = (l15 >> 1) & 3;                       // frag-index independent
  const int aoffB = (waveM * 128 + l15) * 64 + ((g4 ^ sel) << 4);
  const int boffB = 16384 + (waveN * 64 + l15) * 64 + ((g4 ^ sel) << 4);

  // prologue: stage tiles 0,1 (8 loads); tile 0 complete when vmcnt<=4
  STAGE_A(0); STAGE_B(0); STAGE_A(1); STAGE_B(1);
  asm volatile("s_waitcnt vmcnt(4)" ::: "memory");
  __builtin_amdgcn_s_barrier();
  asm volatile("" ::: "memory");

  for (int t = 0; t < NT; ++t) {
    const char* sb = lds + (t & 3) * 32768;
    bf16x8 af[4], bfr[4];
    // ---- phase 1: quadrant m0-3 x n0-3 ----
    #pragma unroll
    for (int m = 0; m < 4; ++m) af[m] = *(const bf16x8*)(sb + aoffB + m * 1024);
    #pragma unroll
    for (int n = 0; n < 4; ++n) bfr[n] = *(const bf16x8*)(sb + boffB + n * 1024);
    if (t + 2 < NT) STAGE_A(t + 2);
    __builtin_amdgcn_s_barrier();
    asm volatile("" ::: "memory");
    __builtin_amdgcn_s_setprio(1);
    #pragma unroll
    for (int m = 0; m < 4; ++m)
      #pragma unroll
      for (int n = 0; n < 4; ++n)
        acc[m][n] = __builtin_amdgcn_mfma_f32_16x16x32_bf16(af[m], bfr[n], acc[m][n], 0, 0, 0);
    __builtin_amdgcn_s_setprio(0);
    __builtin_amdgcn_s_barrier();
    asm volatile("" ::: "memory");
    // ---- phase 2: quadrant m4-7 x n0-3 (reuse B frags) ----
    #pragma unroll
    for (int m = 0; m < 4; ++m) af[m] = *(const bf16x8*)(sb + aoffB + 4096 + m * 1024);
    if (t + 2 < NT) STAGE_B(t + 2);
    __builtin_amdgcn_s_barrier();
    asm volatile("" ::: "memory");
    __builtin_amdgcn_s_setprio(1);
    #pragma unroll
    for (int m = 0; m < 4; ++m)
      #pragma unroll
      for (int n = 0; n < 4; ++n)
        acc[4 + m][n] = __builtin_amdgcn_mfma_f32_16x16x32_bf16(af[m], bfr[n], acc[4 + m][n], 0, 0, 0);
    __builtin_amdgcn_s_setprio(0);
    // counted wait: tile t+1's 4 loads (issued last tile) must be done; t+2's stay in flight
    if (t + 2 < NT) asm volatile("s_waitcnt vmcnt(4)" ::: "memory");
    else            asm volatile("s_waitcnt vmcnt(0)" ::: "memory");
    __builtin_amdgcn_s_barrier();
    asm volatile("" ::: "memory");
  }
#undef STAGE_A
#undef STAGE_B
#undef GLL

  // ---- fused epilogue: poincare dist via log2/exp2, exp-sums, dist sums ----
  const float lt = *p_log_tau;
  const float mg = *p_margin;
  const float marg = fmaxf(mg, 0.f);
  const float tau = 1.99f / (1.f + __expf(-lt)) + 0.01f;
  const float nl = -LN2F / tau;            // exp(L2*nl) == exp2(-L2/tau) == exp(-dist/tau)
  const float em = __expf(-marg);          // diagonal exp correction factor
  const bool diagblk = (bx == by);

  float yyj[4], rcpy[4]; int gj[4];
  #pragma unroll
  for (int n = 0; n < 4; ++n) {
    gj[n] = blockCol + waveN * 64 + n * 16 + l15;        // C/D col = lane&15
    yyj[n] = yy[gj[n]];
    rcpy[n] = __builtin_amdgcn_rcpf(1.f - yyj[n]);
  }

  float dL = 0.f, dDiagL = 0.f;            // dist sums in log2 units
  float* rsum = (float*)lds;               // reuse LDS: [256 rows][4 waveN] partials

  #pragma unroll
  for (int m = 0; m < 8; ++m) {
    #pragma unroll
    for (int r = 0; r < 4; ++r) {
      const int gi = blockRow + waveM * 128 + m * 16 + g4 * 4 + r;  // C/D row
      const float xxi = xx[gi];
      const float p2 = 2.f * __builtin_amdgcn_rcpf(1.f - xxi);
      float e_acc = 0.f;
      #pragma unroll
      for (int n = 0; n < 4; ++n) {
        const float xy = acc[m][n][r];
        const float sq = fmaxf(xxi + yyj[n] - 2.f * xy, 0.f);
        const float tt = sq * (p2 * rcpy[n]);            // arg = 1 + tt
        const float s = __builtin_amdgcn_sqrtf(tt * (tt + 2.f));
        const float w = tt + 1.f + s;                    // arg + sqrt(arg^2-1)
        const float L2 = __log2f(fmaxf(w, 1.f + EPSF));  // dist = L2 * ln2
        float e = __expf(L2 * nl);
        dL += L2;
        if (diagblk && gi == gj[n]) { dDiagL += L2; e *= em; }
        e_acc += e;
      }
      e_acc += __shfl_xor(e_acc, 1);
      e_acc += __shfl_xor(e_acc, 2);
      e_acc += __shfl_xor(e_acc, 4);
      e_acc += __shfl_xor(e_acc, 8);
      if (l15 == 0) {
        const int rloc = waveM * 128 + m * 16 + g4 * 4 + r;
        rsum[rloc * 4 + waveN] = e_acc;
      }
    }
  }

  // block-level scalar reductions -> 2 atomics per wave (log2 units)
  #pragma unroll
  for (int off = 32; off; off >>= 1) {
    dL += __shfl_down(dL, off);
    dDiagL += __shfl_down(dDiagL, off);
  }
  if (lane == 0) {
    atomicAdd(&accums[0], dL);
    if (diagblk) atomicAdd(&accums[1], dDiagL);
  }

  __syncthreads();
  if (tid < 256) {
    const float rs = rsum[tid * 4 + 0] + rsum[tid * 4 + 1] + rsum[tid * 4 + 2] + rsum[tid * 4 + 3];
    row_partial[(size_t)bx * BN + blockRow + tid] = rs;
  }
}

// ---------------- finalize: sum col-tile partials, log, final linear combo ----------------
__global__ __launch_bounds__(1024) void finalize_kernel(
    const float* __restrict__ row_partial, const float* __restrict__ accums,
    const float* __restrict__ p_log_tau, const float* __restrict__ p_margin,
    float* __restrict__ out) {
  const int t = threadIdx.x;
  float lsum = 0.f;
  for (int i = t; i < BN; i += 1024) {
    float s = 0.f;
    #pragma unroll
    for (int c = 0; c < 32; ++c) s += row_partial[(size_t)c * BN + i];
    lsum += __logf(s);
  }
  #pragma unroll
  for (int off = 32; off; off >>= 1) lsum += __shfl_down(lsum, off);
  __shared__ float red[16];
  if ((t & 63) == 0) red[t >> 6] = lsum;
  __syncthreads();
  if (t == 0) {
    float total = 0.f;
    #pragma unroll
    for (int w = 0; w < 16; ++w) total += red[w];
    const float lt = *p_log_tau;
    const float mg = *p_margin;
    const float marg = fmaxf(mg, 0.f);
    const float tau = 1.99f / (1.f + __expf(-lt)) + 0.01f;
    const float C = marg;
    const float d_tot = accums[0] * LN2F;
    const float d_diag = accums[1] * LN2F;
    const float bf = (float)BN;
    const float mean_lse = total / bf + C;
    const float sum_scores = -d_tot / tau + marg * (bf * bf - bf);  // margin term closed-form
    const float sum_diag_scores = -d_diag / tau;
    const float loss = mean_lse
                     - (1.f - LSMOOTH) * (sum_diag_scores / bf)
                     - LSMOOTH * (sum_scores / (bf * bf));
    out[0] = loss;
    out[1] = d_diag / bf;   // pos_dist
    out[2] = tau;
    out[3] = mg;            // maximum(margin, margin) == margin
  }
}

extern "C" void kernel_launch(void* const* d_in, const int* in_sizes, int n_in,
                              void* d_out, int out_size, void* d_ws, size_t ws_size,
                              hipStream_t stream) {
  const float* sign = (const float*)d_in[0];
  const float* text = (const float*)d_in[1];
  const float* p_log_tau = (const float*)d_in[2];
  const float* p_margin = (const float*)d_in[3];
  float* out = (float*)d_out;

  char* ws = (char*)d_ws;
  unsigned short* Abf = (unsigned short*)ws;                         // 16 MiB
  unsigned short* Bbf = (unsigned short*)(ws + (size_t)BN * DK * 2); // 16 MiB
  float* xx = (float*)(ws + (size_t)BN * DK * 4);
  float* yy = xx + BN;
  float* row_partial = yy + BN;                                      // 32 x 8192 floats
  float* accums = row_partial + 32 * BN;                             // 2 floats

  hipMemsetAsync(accums, 0, 2 * sizeof(float), stream);
  prep_kernel<<<dim3(2 * BN), 256, 0, stream>>>(sign, text, Abf, Bbf, xx, yy);
  gemm_fused<<<dim3(BN / 256, BN / 256), 512, 0, stream>>>(
      Abf, Bbf, xx, yy, p_log_tau, p_margin, row_partial, accums);
  finalize_kernel<<<1, 1024, 0, stream>>>(row_partial, accums, p_log_tau, p_margin, out);
}